// Round 6
// baseline (198.671 us; speedup 1.0000x reference)
//
#include <hip/hip_runtime.h>

typedef unsigned short u16;
typedef unsigned int u32;
typedef __attribute__((ext_vector_type(8))) short s16x8;
typedef __attribute__((ext_vector_type(4))) float f32x4;

#define MFMA16(a,b,c) __builtin_amdgcn_mfma_f32_16x16x32_bf16(a,b,c,0,0,0)

__device__ __forceinline__ u16 f2bf(float f){
  u32 u = __builtin_bit_cast(u32, f);
  return (u16)((u + 0x7FFFu + ((u >> 16) & 1u)) >> 16);
}
__device__ __forceinline__ float b2f(u16 s){
  u32 u = ((u32)s) << 16;
  return __builtin_bit_cast(float, u);
}
__device__ __forceinline__ void async16(const void* g, void* l){
  __builtin_amdgcn_global_load_lds((const __attribute__((address_space(1))) u32*)g,
                                   (__attribute__((address_space(3))) u32*)l, 16, 0, 0);
}

// B=4, N=4096, C=512, H=8, d=64, K=64. Tokens M=16384, out-channels OC=2048.
// QKVV ws layout: [o][m], o = g*512 + h*64 + dd (g: q,k,vCA,vSA), m = b*4096 + n.
// 64-wide bf16 LDS tiles: 16B-slot s at row r lives at s ^ (r&7) (8 slots/row).

// ---- kernel 0: convert x,W -> bf16; EF -> bf16 transposed [64][4096] ----
__global__ __launch_bounds__(256) void k_convert(const float4* __restrict__ x4,
                                                 const float4* __restrict__ w4,
                                                 const float* __restrict__ EF,
                                                 u16* __restrict__ Xb, u16* __restrict__ Wb,
                                                 u16* __restrict__ EFt){
  int i = blockIdx.x * 256 + threadIdx.x;
  if (i < 2097152){
    float4 v = x4[i];
    u32 lo = (u32)f2bf(v.x) | ((u32)f2bf(v.y) << 16);
    u32 hi = (u32)f2bf(v.z) | ((u32)f2bf(v.w) << 16);
    *(uint2*)(&Xb[(size_t)i*4]) = make_uint2(lo, hi);
  } else if (i < 2097152 + 262144){
    int j = i - 2097152;
    float4 v = w4[j];
    u32 lo = (u32)f2bf(v.x) | ((u32)f2bf(v.y) << 16);
    u32 hi = (u32)f2bf(v.z) | ((u32)f2bf(v.w) << 16);
    *(uint2*)(&Wb[(size_t)j*4]) = make_uint2(lo, hi);
  } else if (i < 2097152 + 262144 + 262144){
    int j = i - 2097152 - 262144;
    int kk = j >> 12, nn = j & 4095;
    EFt[(size_t)kk*4096 + nn] = f2bf(EF[(size_t)nn*64 + kk]);
  }
}

// ---- kernel 1: QKVV GEMM, 256x256 tile, BK=64, 8 waves, dbuf + phase schedule ----
// Out[o][m] = sum_c Wb[o][c]*Xb[m][c]. Grid 512 = 8 ot x 64 mt, XCD-chunked.
__global__ __launch_bounds__(512, 2) void k_gemm(const u16* __restrict__ Wb,
                                                 const u16* __restrict__ Xb,
                                                 u16* __restrict__ Out){
  __shared__ u16 As[2][2][128*64];   // [dbuf][half][row*64 + col]
  __shared__ u16 Bs[2][2][128*64];
  int bid = blockIdx.x;
  int sbid = (bid & 7) * 64 + (bid >> 3);   // XCD x -> sbid in [x*64, x*64+64)
  int ot = sbid >> 6, mt = sbid & 63;
  int o0 = ot * 256, m0 = mt * 256;
  int t = threadIdx.x;
  int lane = t & 63, wid = t >> 6;
  int wr = wid >> 2, wc = wid & 3;          // 2 x 4 wave grid; wave owns 128(o) x 64(m)
  int l15 = lane & 15, l4 = lane >> 4;

  // Staging: idx = c*512+t -> row = c*64 + (t>>3) in [0,128), lds slot = t&7.
  // LDS dest bytes = idx*16 (wave-contiguous); global col-slot = (t&7)^(row&7).
#define STAGE_TILE(kt_, db_)                                                    \
  {                                                                             \
    int kb_ = (kt_) * 64;                                                       \
    int srow_ = t >> 3, sg_ = (t & 7) ^ (srow_ & 7);                            \
    _Pragma("unroll")                                                           \
    for (int hf = 0; hf < 2; ++hf){                                             \
      _Pragma("unroll")                                                         \
      for (int c = 0; c < 2; ++c){                                              \
        int row = c*64 + srow_;                                                 \
        async16(Wb + (size_t)(o0 + hf*128 + row) * 512 + kb_ + sg_*8,           \
                &As[db_][hf][row*64 + (t & 7)*8]);                              \
        async16(Xb + (size_t)(m0 + hf*128 + row) * 512 + kb_ + sg_*8,           \
                &Bs[db_][hf][row*64 + (t & 7)*8]);                              \
      }                                                                         \
    }                                                                           \
  }

  f32x4 acc[8][4];
#pragma unroll
  for (int a = 0; a < 8; ++a)
#pragma unroll
    for (int b = 0; b < 4; ++b) acc[a][b] = (f32x4){0.f, 0.f, 0.f, 0.f};

  STAGE_TILE(0, 0);
  asm volatile("s_waitcnt vmcnt(0)" ::: "memory");
  __builtin_amdgcn_s_barrier();
  asm volatile("" ::: "memory");

  s16x8 bfr[4];
  for (int kt = 0; kt < 8; ++kt){
    int db = kt & 1;
    const u16* Abase = &As[db][wr][0];
    const u16* Bbase = &Bs[db][wc >> 1][0];
#pragma unroll
    for (int p = 0; p < 4; ++p){
      const int ks = p >> 1, rfh = p & 1;
      s16x8 af[4];
#pragma unroll
      for (int i = 0; i < 4; ++i){
        int row = (rfh*4 + i)*16 + l15;
        af[i] = *(const s16x8*)(Abase + row*64 + ((ks*4 + l4) ^ (row & 7))*8);
      }
      if (rfh == 0){
#pragma unroll
        for (int cf = 0; cf < 4; ++cf){
          int row = (wc & 1)*64 + cf*16 + l15;
          bfr[cf] = *(const s16x8*)(Bbase + row*64 + ((ks*4 + l4) ^ (row & 7))*8);
        }
      }
      if (p == 0 && kt < 7) STAGE_TILE(kt + 1, db ^ 1);
      __builtin_amdgcn_s_barrier();
      asm volatile("" ::: "memory");
      __builtin_amdgcn_s_setprio(1);
#pragma unroll
      for (int i = 0; i < 4; ++i)
#pragma unroll
        for (int cf = 0; cf < 4; ++cf)
          acc[rfh*4 + i][cf] = MFMA16(af[i], bfr[cf], acc[rfh*4 + i][cf]);
      __builtin_amdgcn_s_setprio(0);
      if (p == 3 && kt < 7) asm volatile("s_waitcnt vmcnt(0)" ::: "memory");
      __builtin_amdgcn_s_barrier();
      asm volatile("" ::: "memory");
    }
  }
#undef STAGE_TILE

#pragma unroll
  for (int rf = 0; rf < 8; ++rf)
#pragma unroll
    for (int cf = 0; cf < 4; ++cf){
      int o = o0 + wr*128 + rf*16 + l4*4;
      int m = m0 + wc*64 + cf*16 + l15;
#pragma unroll
      for (int r = 0; r < 4; ++r) Out[(size_t)(o + r) * 16384 + m] = f2bf(acc[rf][cf][r]);
    }
}

// ---- kernel 2: reciprocal L2 norms of q,k rows over token axis (wave per row) ----
__global__ __launch_bounds__(256) void k_rnorm(const u16* __restrict__ QK,
                                               float* __restrict__ rq, float* __restrict__ rk){
  int job = blockIdx.x * 4 + (threadIdx.x >> 6);  // 4096 jobs
  int o = job >> 2, b = job & 3;
  int lane = threadIdx.x & 63;
  const u16* row = QK + (size_t)o * 16384 + (size_t)b * 4096;
  float s = 0.f;
#pragma unroll
  for (int it = 0; it < 8; ++it){
    s16x8 v = *(const s16x8*)(&row[it * 512 + lane * 8]);
#pragma unroll
    for (int j = 0; j < 8; ++j){ float f = b2f((u16)v[j]); s += f * f; }
  }
  for (int off = 32; off; off >>= 1) s += __shfl_down(s, off);
  if (lane == 0){
    float r = 1.f / fmaxf(sqrtf(s), 1e-12f);
    if (o < 512) rq[b * 512 + o] = r;
    else         rk[b * 512 + (o - 512)] = r;
  }
}

// ---- kernel 3: partial contractions over 512-token splits ----
// grid 768 = p*256 + bh*8 + s; p: 0 = q.kT, 1 = k.EF ([kk][dd]), 2 = vSA.EF ([dd][kk])
__global__ __launch_bounds__(256) void k_acc1(const u16* __restrict__ QK,
                                              const u16* __restrict__ EFt,
                                              float* __restrict__ Pp){
  __shared__ u16 Ab[2][64*128];
  __shared__ u16 Bb[2][64*128];
  int bid = blockIdx.x;
  int p = bid >> 8;
  int rem = bid & 255;
  int bh = rem >> 3, s = rem & 7;
  int b = bh >> 3, h = bh & 7;
  int t = threadIdx.x, lane = t & 63, w = t >> 6, l15 = lane & 15, l4 = lane >> 4;
  int abase = (p == 0 ? 0 : (p == 1 ? 512 : 1536)) + h * 64;
  const u16* Aglob = QK + (size_t)abase * 16384 + (size_t)b * 4096 + s * 512;
  const u16* Bglob;
  size_t bstride;
  if (p == 0){ Bglob = QK + (size_t)(512 + h*64) * 16384 + (size_t)b * 4096 + s * 512; bstride = 16384; }
  else       { Bglob = EFt + s * 512; bstride = 4096; }
  int srow = t >> 4, sslot = t & 15;

#define STAGE_ACC(ch, buf)                                                        \
  {                                                                               \
    int n0_ = (ch) * 128;                                                         \
    _Pragma("unroll")                                                             \
    for (int c = 0; c < 4; ++c){                                                  \
      int row = c*16 + srow;                                                      \
      int sg = sslot ^ (row & 7);                                                 \
      async16(Aglob + (size_t)row * 16384 + n0_ + sg*8, &Ab[buf][row*128 + sslot*8]); \
    }                                                                             \
    _Pragma("unroll")                                                             \
    for (int c = 0; c < 4; ++c){                                                  \
      int row = c*16 + srow;                                                      \
      int sg = sslot ^ (row & 7);                                                 \
      async16(Bglob + (size_t)row * bstride + n0_ + sg*8, &Bb[buf][row*128 + sslot*8]); \
    }                                                                             \
  }

  f32x4 acc[4];
#pragma unroll
  for (int c = 0; c < 4; ++c) acc[c] = (f32x4){0.f,0.f,0.f,0.f};

  STAGE_ACC(0, 0);
#pragma unroll
  for (int ch = 0; ch < 4; ++ch){
    int buf = ch & 1;
    if (ch < 3){
      STAGE_ACC(ch + 1, buf ^ 1);
      asm volatile("s_waitcnt vmcnt(8)" ::: "memory");
    } else {
      asm volatile("s_waitcnt vmcnt(0)" ::: "memory");
    }
    __builtin_amdgcn_s_barrier();
    asm volatile("" ::: "memory");
    int arow = w*16 + l15;
#pragma unroll
    for (int ks = 0; ks < 4; ++ks){
      s16x8 a = *(const s16x8*)(&Ab[buf][arow*128 + (((ks*4 + l4) ^ (arow & 7)))*8]);
#pragma unroll
      for (int cf = 0; cf < 4; ++cf){
        int brow = cf*16 + l15;
        s16x8 bb = *(const s16x8*)(&Bb[buf][brow*128 + (((ks*4 + l4) ^ (brow & 7)))*8]);
        acc[cf] = MFMA16(a, bb, acc[cf]);
      }
    }
    __builtin_amdgcn_s_barrier();
    asm volatile("" ::: "memory");
  }

  float* out = Pp + ((size_t)(bh * 3 + p) * 8 + s) * 4096;
#pragma unroll
  for (int cf = 0; cf < 4; ++cf)
#pragma unroll
    for (int r = 0; r < 4; ++r){
      int rr = w*16 + l4*4 + r;
      int cc = cf*16 + l15;
      int off = (p == 1) ? (cc * 64 + rr) : (rr * 64 + cc);
      out[off] = acc[cf][r];
    }
#undef STAGE_ACC
}

// ---- kernel 4: reduce partials; softmax(S)->Pca; kp*rq*t2->kpb; vp->vpb ----
// Outputs written PRE-SWIZZLED (slot s at row r stored at s^(r&7)) for linear gload_lds.
__global__ __launch_bounds__(256) void k_fin(const float* __restrict__ Pp,
                                             const float* __restrict__ rq,
                                             const float* __restrict__ rk,
                                             const float* __restrict__ t1,
                                             const float* __restrict__ t2,
                                             u16* __restrict__ Pca,
                                             u16* __restrict__ kpb,
                                             u16* __restrict__ vpb){
  int bh = blockIdx.x;
  int b = bh >> 3, h = bh & 7;
  int t = threadIdx.x;
  int row = t >> 2, q4 = t & 3;
  const float* base = Pp + (size_t)bh * 3 * 8 * 4096;
  float t1h = t1[h], t2h = t2[h];
  const float* rqh = rq + b*512 + h*64;
  const float* rkh = rk + b*512 + h*64;
  int sA = (((q4*2)     ^ (row & 7)) << 3);
  int sB = (((q4*2 + 1) ^ (row & 7)) << 3);

  // ---- product 0: S = q.kT -> scale -> softmax -> Pca
  {
    float v[16];
#pragma unroll
    for (int i = 0; i < 4; ++i){
      f32x4 a = (f32x4){0.f,0.f,0.f,0.f};
#pragma unroll
      for (int s = 0; s < 8; ++s)
        a += *(const f32x4*)(base + (size_t)s * 4096 + t*16 + i*4);
#pragma unroll
      for (int j = 0; j < 4; ++j) v[i*4 + j] = a[j];
    }
    float sq = rqh[row] * t1h;
#pragma unroll
    for (int e = 0; e < 16; ++e) v[e] *= sq * rkh[q4*16 + e];
    float mx = v[0];
#pragma unroll
    for (int e = 1; e < 16; ++e) mx = fmaxf(mx, v[e]);
    mx = fmaxf(mx, __shfl_xor(mx, 1));
    mx = fmaxf(mx, __shfl_xor(mx, 2));
    float sum = 0.f;
#pragma unroll
    for (int e = 0; e < 16; ++e){ v[e] = __expf(v[e] - mx); sum += v[e]; }
    sum += __shfl_xor(sum, 1);
    sum += __shfl_xor(sum, 2);
    float inv = 1.f / sum;
    s16x8 o0, o1;
#pragma unroll
    for (int e = 0; e < 8; ++e){ o0[e] = (short)f2bf(v[e] * inv); o1[e] = (short)f2bf(v[8+e] * inv); }
    *(s16x8*)(&Pca[(size_t)bh*4096 + row*64 + sA]) = o0;
    *(s16x8*)(&Pca[(size_t)bh*4096 + row*64 + sB]) = o1;
  }
  // ---- product 1: kp [kk][dd], scale rq[dd]*t2
  {
    const float* p1 = base + 8 * 4096;
    float v[16];
#pragma unroll
    for (int i = 0; i < 4; ++i){
      f32x4 a = (f32x4){0.f,0.f,0.f,0.f};
#pragma unroll
      for (int s = 0; s < 8; ++s)
        a += *(const f32x4*)(p1 + (size_t)s * 4096 + t*16 + i*4);
#pragma unroll
      for (int j = 0; j < 4; ++j) v[i*4 + j] = a[j];
    }
    s16x8 o0, o1;
#pragma unroll
    for (int e = 0; e < 8; ++e){
      o0[e] = (short)f2bf(v[e]   * rqh[q4*16 + e]     * t2h);
      o1[e] = (short)f2bf(v[8+e] * rqh[q4*16 + 8 + e] * t2h);
    }
    *(s16x8*)(&kpb[(size_t)bh*4096 + row*64 + sA]) = o0;
    *(s16x8*)(&kpb[(size_t)bh*4096 + row*64 + sB]) = o1;
  }
  // ---- product 2: vp [dd][kk], no scale
  {
    const float* p2 = base + 16 * 4096;
    float v[16];
#pragma unroll
    for (int i = 0; i < 4; ++i){
      f32x4 a = (f32x4){0.f,0.f,0.f,0.f};
#pragma unroll
      for (int s = 0; s < 8; ++s)
        a += *(const f32x4*)(p2 + (size_t)s * 4096 + t*16 + i*4);
#pragma unroll
      for (int j = 0; j < 4; ++j) v[i*4 + j] = a[j];
    }
    s16x8 o0, o1;
#pragma unroll
    for (int e = 0; e < 8; ++e){ o0[e] = (short)f2bf(v[e]); o1[e] = (short)f2bf(v[8+e]); }
    *(s16x8*)(&vpb[(size_t)bh*4096 + row*64 + sA]) = o0;
    *(s16x8*)(&vpb[(size_t)bh*4096 + row*64 + sB]) = o1;
  }
}

// ---- kernel 5: x_CA = P @ V_CA per 64-token chunk; overwrite out[b][n][h*64+dd] ----
__global__ __launch_bounds__(256) void k_ca_pv(const u16* __restrict__ QK,
                                               const u16* __restrict__ Pca,
                                               float* __restrict__ out){
  __shared__ u16 Pl[64*64];      // pre-swizzled, linear copy
  __shared__ u16 Vt[64*64];      // [j][e], swizzled, transpose-staged
  __shared__ float Sx[64*64];
  int bid = blockIdx.x;          // 2048 = bh*64 + ch
  int ch = bid & 63, bh = bid >> 6, b = bh >> 3, h = bh & 7;
  int n0 = ch * 64;
  int t = threadIdx.x, lane = t & 63, w = t >> 6, l15 = lane & 15, l4 = lane >> 4;
  {
    const u16* src = Pca + (size_t)bh * 4096;
#pragma unroll
    for (int c = 0; c < 2; ++c)
      async16(src + (c*256 + t)*8, &Pl[(c*256 + t)*8]);
  }
  const u16* Vg = QK + (size_t)(1024 + h*64) * 16384 + (size_t)b*4096 + n0;
#pragma unroll
  for (int pass = 0; pass < 2; ++pass){
    int idx = pass*256 + t;
    int e = idx >> 3, j0 = (idx & 7) * 8, g = idx & 7;
    s16x8 v = *(const s16x8*)(Vg + (size_t)e * 16384 + j0);
#pragma unroll
    for (int i = 0; i < 8; ++i){
      int jj = (i + e + g) & 7;         // bank-derotated write order (2-way, free)
      int j = j0 + jj;
      Vt[j*64 + ((((e>>3) ^ jj)) << 3) + (e & 7)] = (u16)v[jj];
    }
  }
  __syncthreads();
  f32x4 acc[4];
#pragma unroll
  for (int c = 0; c < 4; ++c) acc[c] = (f32x4){0.f,0.f,0.f,0.f};
  int ar = w*16 + l15;
#pragma unroll
  for (int ks = 0; ks < 2; ++ks){
    s16x8 a = *(const s16x8*)(&Pl[ar*64 + (((ks*4 + l4) ^ (ar & 7)))*8]);
#pragma unroll
    for (int cf = 0; cf < 4; ++cf){
      int br = cf*16 + l15;
      s16x8 bb = *(const s16x8*)(&Vt[br*64 + (((ks*4 + l4) ^ (br & 7)))*8]);
      acc[cf] = MFMA16(a, bb, acc[cf]);
    }
  }
#pragma unroll
  for (int cf = 0; cf < 4; ++cf)
#pragma unroll
    for (int r = 0; r < 4; ++r){
      int d = w*16 + l4*4 + r, j = cf*16 + l15;
      Sx[j*64 + d] = acc[cf][r];
    }
  __syncthreads();
#pragma unroll
  for (int i = 0; i < 4; ++i){
    int idx = t + 256 * i;
    int j = idx >> 4, v = idx & 15;
    float4 val;
    val.x = Sx[j*64 + v*4 + 0]; val.y = Sx[j*64 + v*4 + 1];
    val.z = Sx[j*64 + v*4 + 2]; val.w = Sx[j*64 + v*4 + 3];
    *(float4*)(&out[((size_t)(b*4096 + n0 + j)) * 512 + h*64 + v*4]) = val;
  }
}

// ---- kernel 6: spatial attention per 64-token chunk; out += faithful-bug scatter ----
__global__ __launch_bounds__(256) void k_sa(const u16* __restrict__ QK,
                                            const u16* __restrict__ kpb,
                                            const u16* __restrict__ vpb,
                                            float* __restrict__ out){
  __shared__ u16 Qt[64*64];      // Q^T [j][dd] swizzled; reused as P [j][kk] swizzled
  __shared__ u16 kpl[64*64];     // [kk][dd] pre-swizzled
  __shared__ u16 vpl[64*64];     // [dd][kk] pre-swizzled
  __shared__ float Sf[64*64];    // x_SA^T staging
  int bid = blockIdx.x;          // 2048 = bh*64 + ch
  int ch = bid & 63, bh = bid >> 6, b = bh >> 3, h = bh & 7;
  int n0 = ch * 64;
  int t = threadIdx.x, lane = t & 63, w = t >> 6, l15 = lane & 15, l4 = lane >> 4;
#pragma unroll
  for (int c = 0; c < 2; ++c){
    async16(kpb + (size_t)bh*4096 + (c*256 + t)*8, &kpl[(c*256 + t)*8]);
    async16(vpb + (size_t)bh*4096 + (c*256 + t)*8, &vpl[(c*256 + t)*8]);
  }
  const u16* Qg = QK + (size_t)(h*64) * 16384 + (size_t)b*4096 + n0;
#pragma unroll
  for (int pass = 0; pass < 2; ++pass){
    int idx = pass*256 + t;
    int dd = idx >> 3, j0 = (idx & 7) * 8, g = idx & 7;
    s16x8 v = *(const s16x8*)(Qg + (size_t)dd * 16384 + j0);
#pragma unroll
    for (int i = 0; i < 8; ++i){
      int jj = (i + dd + g) & 7;        // bank-derotated write order
      int j = j0 + jj;
      Qt[j*64 + ((((dd>>3) ^ jj)) << 3) + (dd & 7)] = (u16)v[jj];
    }
  }
  __syncthreads();
  // QK^T: C[j][kk]
  f32x4 acc[4];
#pragma unroll
  for (int c = 0; c < 4; ++c) acc[c] = (f32x4){0.f,0.f,0.f,0.f};
  int ar = w*16 + l15;
#pragma unroll
  for (int ks = 0; ks < 2; ++ks){
    s16x8 a = *(const s16x8*)(&Qt[ar*64 + (((ks*4 + l4) ^ (ar & 7)))*8]);
#pragma unroll
    for (int cf = 0; cf < 4; ++cf){
      int br = cf*16 + l15;
      s16x8 bb = *(const s16x8*)(&kpl[br*64 + (((ks*4 + l4) ^ (br & 7)))*8]);
      acc[cf] = MFMA16(a, bb, acc[cf]);
    }
  }
  // register softmax over kk per row j = w*16+l4*4+r
#pragma unroll
  for (int r = 0; r < 4; ++r){
    float mx = fmaxf(fmaxf(acc[0][r], acc[1][r]), fmaxf(acc[2][r], acc[3][r]));
    mx = fmaxf(mx, __shfl_xor(mx, 1));
    mx = fmaxf(mx, __shfl_xor(mx, 2));
    mx = fmaxf(mx, __shfl_xor(mx, 4));
    mx = fmaxf(mx, __shfl_xor(mx, 8));
    float sum = 0.f;
#pragma unroll
    for (int cf = 0; cf < 4; ++cf){ acc[cf][r] = __expf(acc[cf][r] - mx); sum += acc[cf][r]; }
    sum += __shfl_xor(sum, 1);
    sum += __shfl_xor(sum, 2);
    sum += __shfl_xor(sum, 4);
    sum += __shfl_xor(sum, 8);
    float inv = 1.f / sum;
#pragma unroll
    for (int cf = 0; cf < 4; ++cf) acc[cf][r] *= inv;
  }
  // write P into Qt (own band only; same-wave rows)
#pragma unroll
  for (int cf = 0; cf < 4; ++cf)
#pragma unroll
    for (int r = 0; r < 4; ++r){
      int j = w*16 + l4*4 + r;
      int kslot = cf*2 + (l15 >> 3);
      Qt[j*64 + ((kslot ^ (j & 7)) << 3) + (l15 & 7)] = f2bf(acc[cf][r]);
    }
  __syncthreads();
  // PV: C[j][dd] = sum_kk P[j][kk] * vpl[dd][kk]
  f32x4 acc2[4];
#pragma unroll
  for (int c = 0; c < 4; ++c) acc2[c] = (f32x4){0.f,0.f,0.f,0.f};
#pragma unroll
  for (int ks = 0; ks < 2; ++ks){
    s16x8 a = *(const s16x8*)(&Qt[ar*64 + (((ks*4 + l4) ^ (ar & 7)))*8]);
#pragma unroll
    for (int cf = 0; cf < 4; ++cf){
      int br = cf*16 + l15;
      s16x8 bb = *(const s16x8*)(&vpl[br*64 + (((ks*4 + l4) ^ (br & 7)))*8]);
      acc2[cf] = MFMA16(a, bb, acc2[cf]);
    }
  }
#pragma unroll
  for (int cf = 0; cf < 4; ++cf)
#pragma unroll
    for (int r = 0; r < 4; ++r){
      int j = w*16 + l4*4 + r, dd = cf*16 + l15;
      Sf[dd*64 + j] = acc2[cf][r];   // x_SA^T [dd][j]
    }
  __syncthreads();
  // faithful-bug scatter: out[b, dd*32768 + h*4096 + n0 + j] += x_SA[n][dd]
#pragma unroll
  for (int i = 0; i < 4; ++i){
    int idx = t + 256 * i;
    int dd = idx >> 4, v = idx & 15;
    size_t p = (size_t)b*2097152 + (size_t)dd*32768 + (size_t)h*4096 + n0 + v*4;
    float4 cur = *(float4*)(&out[p]);
    cur.x += Sf[dd*64 + v*4 + 0]; cur.y += Sf[dd*64 + v*4 + 1];
    cur.z += Sf[dd*64 + v*4 + 2]; cur.w += Sf[dd*64 + v*4 + 3];
    *(float4*)(&out[p]) = cur;
  }
}

extern "C" void kernel_launch(void* const* d_in, const int* in_sizes, int n_in,
                              void* d_out, int out_size, void* d_ws, size_t ws_size,
                              hipStream_t stream) {
  const float* x  = (const float*)d_in[0];
  const float* Wq = (const float*)d_in[1];
  const float* EF = (const float*)d_in[2];
  const float* t1 = (const float*)d_in[3];
  const float* t2 = (const float*)d_in[4];
  float* out = (float*)d_out;

  u16* Xb  = (u16*)d_ws;                 // 16384*512 (dead after k_gemm)
  u16* Wb  = Xb + 8388608;               // 2048*512
  u16* EFt = Wb + 1048576;               // 64*4096
  u16* QK  = EFt + 262144;               // 2048*16384
  float* rq  = (float*)(QK + 33554432);  // 4*512
  float* rk  = rq + 2048;                // 4*512
  u16* kpb = (u16*)(rk + 2048);          // 32*64*64 bf16 [bh][kk][dd], pre-scaled rq*t2, pre-swizzled
  u16* vpb = kpb + 131072;               // 32*64*64 bf16 [bh][dd][kk], pre-swizzled
  u16* Pca = vpb + 131072;               // 32*64*64 bf16, pre-swizzled
  float* Pp = (float*)d_ws;              // partials [bh][3][8][4096] f32, aliases Xb

  k_convert<<<10240, 256, 0, stream>>>((const float4*)x, (const float4*)Wq, EF, Xb, Wb, EFt);
  k_gemm   <<<512,  512, 0, stream>>>(Wb, Xb, QK);
  k_rnorm  <<<1024, 256, 0, stream>>>(QK, rq, rk);
  k_acc1   <<<768,  256, 0, stream>>>(QK, EFt, Pp);
  k_fin    <<<32,   256, 0, stream>>>(Pp, rq, rk, t1, t2, Pca, kpb, vpb);
  k_ca_pv  <<<2048, 256, 0, stream>>>(QK, Pca, out);
  k_sa     <<<2048, 256, 0, stream>>>(QK, kpb, vpb, out);
}

// Round 9
// 191.324 us; speedup vs baseline: 1.0384x; 1.0384x over previous
//
#include <hip/hip_runtime.h>

typedef unsigned short u16;
typedef unsigned int u32;
typedef __attribute__((ext_vector_type(8))) short s16x8;
typedef __attribute__((ext_vector_type(4))) float f32x4;

#define MFMA16(a,b,c) __builtin_amdgcn_mfma_f32_16x16x32_bf16(a,b,c,0,0,0)

__device__ __forceinline__ u16 f2bf(float f){
  u32 u = __builtin_bit_cast(u32, f);
  return (u16)((u + 0x7FFFu + ((u >> 16) & 1u)) >> 16);
}
__device__ __forceinline__ float b2f(u16 s){
  u32 u = ((u32)s) << 16;
  return __builtin_bit_cast(float, u);
}
__device__ __forceinline__ void async16(const void* g, void* l){
  __builtin_amdgcn_global_load_lds((const __attribute__((address_space(1))) u32*)g,
                                   (__attribute__((address_space(3))) u32*)l, 16, 0, 0);
}

// B=4, N=4096, C=512, H=8, d=64, K=64. Tokens M=16384, out-channels OC=2048.
// QKVV ws layout: [o][m], o = g*512 + h*64 + dd (g: q,k,vCA,vSA), m = b*4096 + n.
// 64-wide bf16 LDS tiles: 16B-slot s at row r lives at s ^ (r&7) (8 slots/row).

// ---- kernel 0: convert x,W -> bf16; EF -> bf16 transposed [64][4096] ----
__global__ __launch_bounds__(256) void k_convert(const float4* __restrict__ x4,
                                                 const float4* __restrict__ w4,
                                                 const float* __restrict__ EF,
                                                 u16* __restrict__ Xb, u16* __restrict__ Wb,
                                                 u16* __restrict__ EFt){
  int i = blockIdx.x * 256 + threadIdx.x;
  if (i < 2097152){
    float4 v = x4[i];
    u32 lo = (u32)f2bf(v.x) | ((u32)f2bf(v.y) << 16);
    u32 hi = (u32)f2bf(v.z) | ((u32)f2bf(v.w) << 16);
    *(uint2*)(&Xb[(size_t)i*4]) = make_uint2(lo, hi);
  } else if (i < 2097152 + 262144){
    int j = i - 2097152;
    float4 v = w4[j];
    u32 lo = (u32)f2bf(v.x) | ((u32)f2bf(v.y) << 16);
    u32 hi = (u32)f2bf(v.z) | ((u32)f2bf(v.w) << 16);
    *(uint2*)(&Wb[(size_t)j*4]) = make_uint2(lo, hi);
  } else if (i < 2097152 + 262144 + 262144){
    int j = i - 2097152 - 262144;
    int kk = j >> 12, nn = j & 4095;
    EFt[(size_t)kk*4096 + nn] = f2bf(EF[(size_t)nn*64 + kk]);
  }
}

// ---- kernel 1: QKVV GEMM, 256x256 tile, BK=64, 8 waves, dbuf + phase schedule ----
// Out[o][m] = sum_c Wb[o][c]*Xb[m][c]. Grid 512 = 8 ot x 64 mt.
// XCD x owns ot in [0,8) x mt in [x*8, x*8+8): Wb 2MB + Xb slab 2MB = 4MB ~ L2/XCD.
__global__ __launch_bounds__(512, 2) void k_gemm(const u16* __restrict__ Wb,
                                                 const u16* __restrict__ Xb,
                                                 u16* __restrict__ Out){
  __shared__ u16 As[2][2][128*64];   // [dbuf][half][row*64 + col]
  __shared__ u16 Bs[2][2][128*64];
  int bid = blockIdx.x;
  int x = bid & 7, c = bid >> 3;            // x = XCD (round-robin dispatch)
  int ot = c >> 3, mt = x * 8 + (c & 7);    // square 8x8 chunk per XCD
  int o0 = ot * 256, m0 = mt * 256;
  int t = threadIdx.x;
  int lane = t & 63, wid = t >> 6;
  int wr = wid >> 2, wc = wid & 3;          // 2 x 4 wave grid; wave owns 128(o) x 64(m)
  int l15 = lane & 15, l4 = lane >> 4;

  // Staging: idx = c*512+t -> row = c*64 + (t>>3) in [0,128), lds slot = t&7.
#define STAGE_TILE(kt_, db_)                                                    \
  {                                                                             \
    int kb_ = (kt_) * 64;                                                       \
    int srow_ = t >> 3, sg_ = (t & 7) ^ (srow_ & 7);                            \
    _Pragma("unroll")                                                           \
    for (int hf = 0; hf < 2; ++hf){                                             \
      _Pragma("unroll")                                                         \
      for (int cc = 0; cc < 2; ++cc){                                           \
        int row = cc*64 + srow_;                                                \
        async16(Wb + (size_t)(o0 + hf*128 + row) * 512 + kb_ + sg_*8,           \
                &As[db_][hf][row*64 + (t & 7)*8]);                              \
        async16(Xb + (size_t)(m0 + hf*128 + row) * 512 + kb_ + sg_*8,           \
                &Bs[db_][hf][row*64 + (t & 7)*8]);                              \
      }                                                                         \
    }                                                                           \
  }

  f32x4 acc[8][4];
#pragma unroll
  for (int a = 0; a < 8; ++a)
#pragma unroll
    for (int b = 0; b < 4; ++b) acc[a][b] = (f32x4){0.f, 0.f, 0.f, 0.f};

  STAGE_TILE(0, 0);
  asm volatile("s_waitcnt vmcnt(0)" ::: "memory");
  __builtin_amdgcn_s_barrier();
  asm volatile("" ::: "memory");

  s16x8 bfr[4];
  for (int kt = 0; kt < 8; ++kt){
    int db = kt & 1;
    const u16* Abase = &As[db][wr][0];
    const u16* Bbase = &Bs[db][wc >> 1][0];
#pragma unroll
    for (int p = 0; p < 4; ++p){
      const int ks = p >> 1, rfh = p & 1;
      s16x8 af[4];
#pragma unroll
      for (int i = 0; i < 4; ++i){
        int row = (rfh*4 + i)*16 + l15;
        af[i] = *(const s16x8*)(Abase + row*64 + ((ks*4 + l4) ^ (row & 7))*8);
      }
      if (rfh == 0){
#pragma unroll
        for (int cf = 0; cf < 4; ++cf){
          int row = (wc & 1)*64 + cf*16 + l15;
          bfr[cf] = *(const s16x8*)(Bbase + row*64 + ((ks*4 + l4) ^ (row & 7))*8);
        }
      }
      if (p == 0 && kt < 7) STAGE_TILE(kt + 1, db ^ 1);
      __builtin_amdgcn_s_barrier();
      asm volatile("" ::: "memory");
      __builtin_amdgcn_s_setprio(1);
#pragma unroll
      for (int i = 0; i < 4; ++i)
#pragma unroll
        for (int cf = 0; cf < 4; ++cf)
          acc[rfh*4 + i][cf] = MFMA16(af[i], bfr[cf], acc[rfh*4 + i][cf]);
      __builtin_amdgcn_s_setprio(0);
      if (p == 3 && kt < 7) asm volatile("s_waitcnt vmcnt(0)" ::: "memory");
      __builtin_amdgcn_s_barrier();
      asm volatile("" ::: "memory");
    }
  }
#undef STAGE_TILE

#pragma unroll
  for (int rf = 0; rf < 8; ++rf)
#pragma unroll
    for (int cf = 0; cf < 4; ++cf){
      int o = o0 + wr*128 + rf*16 + l4*4;
      int m = m0 + wc*64 + cf*16 + l15;
#pragma unroll
      for (int r = 0; r < 4; ++r) Out[(size_t)(o + r) * 16384 + m] = f2bf(acc[rf][cf][r]);
    }
}

// ---- kernel 2: reciprocal L2 norms of q,k rows over token axis (wave per row) ----
__global__ __launch_bounds__(256) void k_rnorm(const u16* __restrict__ QK,
                                               float* __restrict__ rq, float* __restrict__ rk){
  int job = blockIdx.x * 4 + (threadIdx.x >> 6);  // 4096 jobs
  int o = job >> 2, b = job & 3;
  int lane = threadIdx.x & 63;
  const u16* row = QK + (size_t)o * 16384 + (size_t)b * 4096;
  float s = 0.f;
#pragma unroll
  for (int it = 0; it < 8; ++it){
    s16x8 v = *(const s16x8*)(&row[it * 512 + lane * 8]);
#pragma unroll
    for (int j = 0; j < 8; ++j){ float f = b2f((u16)v[j]); s += f * f; }
  }
  for (int off = 32; off; off >>= 1) s += __shfl_down(s, off);
  if (lane == 0){
    float r = 1.f / fmaxf(sqrtf(s), 1e-12f);
    if (o < 512) rq[b * 512 + o] = r;
    else         rk[b * 512 + (o - 512)] = r;
  }
}

// ---- kernel 3: partial contractions over 512-token splits ----
// grid 768 = p*256 + bh*8 + s; p: 0 = q.kT, 1 = k.EF ([kk][dd]), 2 = vSA.EF ([dd][kk])
__global__ __launch_bounds__(256) void k_acc1(const u16* __restrict__ QK,
                                              const u16* __restrict__ EFt,
                                              float* __restrict__ Pp){
  __shared__ u16 Ab[2][64*128];
  __shared__ u16 Bb[2][64*128];
  int bid = blockIdx.x;
  int p = bid >> 8;
  int rem = bid & 255;
  int bh = rem >> 3, s = rem & 7;
  int b = bh >> 3, h = bh & 7;
  int t = threadIdx.x, lane = t & 63, w = t >> 6, l15 = lane & 15, l4 = lane >> 4;
  int abase = (p == 0 ? 0 : (p == 1 ? 512 : 1536)) + h * 64;
  const u16* Aglob = QK + (size_t)abase * 16384 + (size_t)b * 4096 + s * 512;
  const u16* Bglob;
  size_t bstride;
  if (p == 0){ Bglob = QK + (size_t)(512 + h*64) * 16384 + (size_t)b * 4096 + s * 512; bstride = 16384; }
  else       { Bglob = EFt + s * 512; bstride = 4096; }
  int srow = t >> 4, sslot = t & 15;

#define STAGE_ACC(ch, buf)                                                        \
  {                                                                               \
    int n0_ = (ch) * 128;                                                         \
    _Pragma("unroll")                                                             \
    for (int c = 0; c < 4; ++c){                                                  \
      int row = c*16 + srow;                                                      \
      int sg = sslot ^ (row & 7);                                                 \
      async16(Aglob + (size_t)row * 16384 + n0_ + sg*8, &Ab[buf][row*128 + sslot*8]); \
    }                                                                             \
    _Pragma("unroll")                                                             \
    for (int c = 0; c < 4; ++c){                                                  \
      int row = c*16 + srow;                                                      \
      int sg = sslot ^ (row & 7);                                                 \
      async16(Bglob + (size_t)row * bstride + n0_ + sg*8, &Bb[buf][row*128 + sslot*8]); \
    }                                                                             \
  }

  f32x4 acc[4];
#pragma unroll
  for (int c = 0; c < 4; ++c) acc[c] = (f32x4){0.f,0.f,0.f,0.f};

  STAGE_ACC(0, 0);
#pragma unroll
  for (int ch = 0; ch < 4; ++ch){
    int buf = ch & 1;
    if (ch < 3){
      STAGE_ACC(ch + 1, buf ^ 1);
      asm volatile("s_waitcnt vmcnt(8)" ::: "memory");
    } else {
      asm volatile("s_waitcnt vmcnt(0)" ::: "memory");
    }
    __builtin_amdgcn_s_barrier();
    asm volatile("" ::: "memory");
    int arow = w*16 + l15;
#pragma unroll
    for (int ks = 0; ks < 4; ++ks){
      s16x8 a = *(const s16x8*)(&Ab[buf][arow*128 + (((ks*4 + l4) ^ (arow & 7)))*8]);
#pragma unroll
      for (int cf = 0; cf < 4; ++cf){
        int brow = cf*16 + l15;
        s16x8 bb = *(const s16x8*)(&Bb[buf][brow*128 + (((ks*4 + l4) ^ (brow & 7)))*8]);
        acc[cf] = MFMA16(a, bb, acc[cf]);
      }
    }
    __builtin_amdgcn_s_barrier();
    asm volatile("" ::: "memory");
  }

  float* out = Pp + ((size_t)(bh * 3 + p) * 8 + s) * 4096;
#pragma unroll
  for (int cf = 0; cf < 4; ++cf)
#pragma unroll
    for (int r = 0; r < 4; ++r){
      int rr = w*16 + l4*4 + r;
      int cc = cf*16 + l15;
      int off = (p == 1) ? (cc * 64 + rr) : (rr * 64 + cc);
      out[off] = acc[cf][r];
    }
#undef STAGE_ACC
}

// ---- kernel 4: reduce partials; softmax(S)->Pca; kp*rq*t2->kpb; vp->vpb ----
// grid 128 = bh*4 + rowgroup; 16 rows/block, 16 thr/row x 4 cols.
// Outputs PRE-SWIZZLED (16B-slot s at row r stored at s^(r&7)) for linear gload_lds.
__global__ __launch_bounds__(256) void k_fin(const float* __restrict__ Pp,
                                             const float* __restrict__ rq,
                                             const float* __restrict__ rk,
                                             const float* __restrict__ t1,
                                             const float* __restrict__ t2,
                                             u16* __restrict__ Pca,
                                             u16* __restrict__ kpb,
                                             u16* __restrict__ vpb){
  int bid = blockIdx.x;
  int bh = bid >> 2, rg = bid & 3;
  int b = bh >> 3, h = bh & 7;
  int t = threadIdx.x;
  int lr = t >> 4, c4 = t & 15;
  int row = rg * 16 + lr;
  const float* base = Pp + (size_t)bh * 3 * 8 * 4096 + row*64 + c4*4;
  float t1h = t1[h], t2h = t2[h];
  const float* rqh = rq + b*512 + h*64;
  const float* rkh = rk + b*512 + h*64;
  // swizzled elem offset of this thread's 4 bf16 at (row, col=c4*4)
  int so = row*64 + (((c4 >> 1) ^ (row & 7)) << 3) + ((c4 & 1) << 2);

  // ---- product 0: S = q.kT -> scale -> softmax -> Pca
  {
    f32x4 a = (f32x4){0.f,0.f,0.f,0.f};
#pragma unroll
    for (int s = 0; s < 8; ++s) a += *(const f32x4*)(base + (size_t)s * 4096);
    float sq = rqh[row] * t1h;
    float v[4];
#pragma unroll
    for (int j = 0; j < 4; ++j) v[j] = a[j] * sq * rkh[c4*4 + j];
    float mx = fmaxf(fmaxf(v[0], v[1]), fmaxf(v[2], v[3]));
    mx = fmaxf(mx, __shfl_xor(mx, 1));
    mx = fmaxf(mx, __shfl_xor(mx, 2));
    mx = fmaxf(mx, __shfl_xor(mx, 4));
    mx = fmaxf(mx, __shfl_xor(mx, 8));
    float sum = 0.f;
#pragma unroll
    for (int j = 0; j < 4; ++j){ v[j] = __expf(v[j] - mx); sum += v[j]; }
    sum += __shfl_xor(sum, 1);
    sum += __shfl_xor(sum, 2);
    sum += __shfl_xor(sum, 4);
    sum += __shfl_xor(sum, 8);
    float inv = 1.f / sum;
    u32 lo = (u32)f2bf(v[0]*inv) | ((u32)f2bf(v[1]*inv) << 16);
    u32 hi = (u32)f2bf(v[2]*inv) | ((u32)f2bf(v[3]*inv) << 16);
    *(uint2*)(&Pca[(size_t)bh*4096 + so]) = make_uint2(lo, hi);
  }
  // ---- product 1: kp [kk][dd] (row=kk, col=dd), scale rq[dd]*t2
  {
    const float* p1 = base + 8 * 4096;
    f32x4 a = (f32x4){0.f,0.f,0.f,0.f};
#pragma unroll
    for (int s = 0; s < 8; ++s) a += *(const f32x4*)(p1 + (size_t)s * 4096);
    float v[4];
#pragma unroll
    for (int j = 0; j < 4; ++j) v[j] = a[j] * rqh[c4*4 + j] * t2h;
    u32 lo = (u32)f2bf(v[0]) | ((u32)f2bf(v[1]) << 16);
    u32 hi = (u32)f2bf(v[2]) | ((u32)f2bf(v[3]) << 16);
    *(uint2*)(&kpb[(size_t)bh*4096 + so]) = make_uint2(lo, hi);
  }
  // ---- product 2: vp [dd][kk], no scale
  {
    const float* p2 = base + 16 * 4096;
    f32x4 a = (f32x4){0.f,0.f,0.f,0.f};
#pragma unroll
    for (int s = 0; s < 8; ++s) a += *(const f32x4*)(p2 + (size_t)s * 4096);
    u32 lo = (u32)f2bf(a[0]) | ((u32)f2bf(a[1]) << 16);
    u32 hi = (u32)f2bf(a[2]) | ((u32)f2bf(a[3]) << 16);
    *(uint2*)(&vpb[(size_t)bh*4096 + so]) = make_uint2(lo, hi);
  }
}

// ---- kernel 5: x_CA = P @ V_CA per 64-token chunk; overwrite out[b][n][h*64+dd] ----
__global__ __launch_bounds__(256) void k_ca_pv(const u16* __restrict__ QK,
                                               const u16* __restrict__ Pca,
                                               float* __restrict__ out){
  __shared__ u16 Pl[64*64];      // pre-swizzled, linear copy
  __shared__ u16 Vt[64*64];      // [j][e], swizzled, transpose-staged
  __shared__ float Sx[64*64];
  int bid = blockIdx.x;          // 2048 = bh*64 + ch
  int ch = bid & 63, bh = bid >> 6, b = bh >> 3, h = bh & 7;
  int n0 = ch * 64;
  int t = threadIdx.x, lane = t & 63, w = t >> 6, l15 = lane & 15, l4 = lane >> 4;
  {
    const u16* src = Pca + (size_t)bh * 4096;
#pragma unroll
    for (int c = 0; c < 2; ++c)
      async16(src + (c*256 + t)*8, &Pl[(c*256 + t)*8]);
  }
  const u16* Vg = QK + (size_t)(1024 + h*64) * 16384 + (size_t)b*4096 + n0;
#pragma unroll
  for (int pass = 0; pass < 2; ++pass){
    int idx = pass*256 + t;
    int e = idx >> 3, j0 = (idx & 7) * 8, g = idx & 7;
    s16x8 v = *(const s16x8*)(Vg + (size_t)e * 16384 + j0);
#pragma unroll
    for (int i = 0; i < 8; ++i){
      int jj = (i + e + g) & 7;         // bank-derotated write order
      int j = j0 + jj;
      Vt[j*64 + ((((e>>3) ^ jj)) << 3) + (e & 7)] = (u16)v[jj];
    }
  }
  __syncthreads();
  f32x4 acc[4];
#pragma unroll
  for (int c = 0; c < 4; ++c) acc[c] = (f32x4){0.f,0.f,0.f,0.f};
  int ar = w*16 + l15;
#pragma unroll
  for (int ks = 0; ks < 2; ++ks){
    s16x8 a = *(const s16x8*)(&Pl[ar*64 + (((ks*4 + l4) ^ (ar & 7)))*8]);
#pragma unroll
    for (int cf = 0; cf < 4; ++cf){
      int br = cf*16 + l15;
      s16x8 bb = *(const s16x8*)(&Vt[br*64 + (((ks*4 + l4) ^ (br & 7)))*8]);
      acc[cf] = MFMA16(a, bb, acc[cf]);
    }
  }
#pragma unroll
  for (int cf = 0; cf < 4; ++cf)
#pragma unroll
    for (int r = 0; r < 4; ++r){
      int d = w*16 + l4*4 + r, j = cf*16 + l15;
      Sx[j*64 + d] = acc[cf][r];
    }
  __syncthreads();
#pragma unroll
  for (int i = 0; i < 4; ++i){
    int idx = t + 256 * i;
    int j = idx >> 4, v = idx & 15;
    float4 val;
    val.x = Sx[j*64 + v*4 + 0]; val.y = Sx[j*64 + v*4 + 1];
    val.z = Sx[j*64 + v*4 + 2]; val.w = Sx[j*64 + v*4 + 3];
    *(float4*)(&out[((size_t)(b*4096 + n0 + j)) * 512 + h*64 + v*4]) = val;
  }
}

// ---- kernel 6: spatial attention per 64-token chunk; out += faithful-bug scatter ----
__global__ __launch_bounds__(256) void k_sa(const u16* __restrict__ QK,
                                            const u16* __restrict__ kpb,
                                            const u16* __restrict__ vpb,
                                            float* __restrict__ out){
  __shared__ u16 Qt[64*64];      // Q^T [j][dd] swizzled; reused as P [j][kk] swizzled
  __shared__ u16 kpl[64*64];     // [kk][dd] pre-swizzled
  __shared__ u16 vpl[64*64];     // [dd][kk] pre-swizzled
  __shared__ float Sf[64*64];    // x_SA^T staging
  int bid = blockIdx.x;          // 2048 = bh*64 + ch
  int ch = bid & 63, bh = bid >> 6, b = bh >> 3, h = bh & 7;
  int n0 = ch * 64;
  int t = threadIdx.x, lane = t & 63, w = t >> 6, l15 = lane & 15, l4 = lane >> 4;
#pragma unroll
  for (int c = 0; c < 2; ++c){
    async16(kpb + (size_t)bh*4096 + (c*256 + t)*8, &kpl[(c*256 + t)*8]);
    async16(vpb + (size_t)bh*4096 + (c*256 + t)*8, &vpl[(c*256 + t)*8]);
  }
  const u16* Qg = QK + (size_t)(h*64) * 16384 + (size_t)b*4096 + n0;
#pragma unroll
  for (int pass = 0; pass < 2; ++pass){
    int idx = pass*256 + t;
    int dd = idx >> 3, j0 = (idx & 7) * 8, g = idx & 7;
    s16x8 v = *(const s16x8*)(Qg + (size_t)dd * 16384 + j0);
#pragma unroll
    for (int i = 0; i < 8; ++i){
      int jj = (i + dd + g) & 7;        // bank-derotated write order
      int j = j0 + jj;
      Qt[j*64 + ((((dd>>3) ^ jj)) << 3) + (dd & 7)] = (u16)v[jj];
    }
  }
  __syncthreads();
  // QK^T: C[j][kk]
  f32x4 acc[4];
#pragma unroll
  for (int c = 0; c < 4; ++c) acc[c] = (f32x4){0.f,0.f,0.f,0.f};
  int ar = w*16 + l15;
#pragma unroll
  for (int ks = 0; ks < 2; ++ks){
    s16x8 a = *(const s16x8*)(&Qt[ar*64 + (((ks*4 + l4) ^ (ar & 7)))*8]);
#pragma unroll
    for (int cf = 0; cf < 4; ++cf){
      int br = cf*16 + l15;
      s16x8 bb = *(const s16x8*)(&kpl[br*64 + (((ks*4 + l4) ^ (br & 7)))*8]);
      acc[cf] = MFMA16(a, bb, acc[cf]);
    }
  }
  // register softmax over kk per row j = w*16+l4*4+r
#pragma unroll
  for (int r = 0; r < 4; ++r){
    float mx = fmaxf(fmaxf(acc[0][r], acc[1][r]), fmaxf(acc[2][r], acc[3][r]));
    mx = fmaxf(mx, __shfl_xor(mx, 1));
    mx = fmaxf(mx, __shfl_xor(mx, 2));
    mx = fmaxf(mx, __shfl_xor(mx, 4));
    mx = fmaxf(mx, __shfl_xor(mx, 8));
    float sum = 0.f;
#pragma unroll
    for (int cf = 0; cf < 4; ++cf){ acc[cf][r] = __expf(acc[cf][r] - mx); sum += acc[cf][r]; }
    sum += __shfl_xor(sum, 1);
    sum += __shfl_xor(sum, 2);
    sum += __shfl_xor(sum, 4);
    sum += __shfl_xor(sum, 8);
    float inv = 1.f / sum;
#pragma unroll
    for (int cf = 0; cf < 4; ++cf) acc[cf][r] *= inv;
  }
  // write P into Qt (own band only; same-wave rows)
#pragma unroll
  for (int cf = 0; cf < 4; ++cf)
#pragma unroll
    for (int r = 0; r < 4; ++r){
      int j = w*16 + l4*4 + r;
      int kslot = cf*2 + (l15 >> 3);
      Qt[j*64 + ((kslot ^ (j & 7)) << 3) + (l15 & 7)] = f2bf(acc[cf][r]);
    }
  __syncthreads();
  // PV: C[j][dd] = sum_kk P[j][kk] * vpl[dd][kk]
  f32x4 acc2[4];
#pragma unroll
  for (int c = 0; c < 4; ++c) acc2[c] = (f32x4){0.f,0.f,0.f,0.f};
#pragma unroll
  for (int ks = 0; ks < 2; ++ks){
    s16x8 a = *(const s16x8*)(&Qt[ar*64 + (((ks*4 + l4) ^ (ar & 7)))*8]);
#pragma unroll
    for (int cf = 0; cf < 4; ++cf){
      int br = cf*16 + l15;
      s16x8 bb = *(const s16x8*)(&vpl[br*64 + (((ks*4 + l4) ^ (br & 7)))*8]);
      acc2[cf] = MFMA16(a, bb, acc2[cf]);
    }
  }
#pragma unroll
  for (int cf = 0; cf < 4; ++cf)
#pragma unroll
    for (int r = 0; r < 4; ++r){
      int j = w*16 + l4*4 + r, dd = cf*16 + l15;
      Sf[dd*64 + j] = acc2[cf][r];   // x_SA^T [dd][j]
    }
  __syncthreads();
  // faithful-bug scatter: out[b, dd*32768 + h*4096 + n0 + j] += x_SA[n][dd]
#pragma unroll
  for (int i = 0; i < 4; ++i){
    int idx = t + 256 * i;
    int dd = idx >> 4, v = idx & 15;
    size_t p = (size_t)b*2097152 + (size_t)dd*32768 + (size_t)h*4096 + n0 + v*4;
    float4 cur = *(float4*)(&out[p]);
    cur.x += Sf[dd*64 + v*4 + 0]; cur.y += Sf[dd*64 + v*4 + 1];
    cur.z += Sf[dd*64 + v*4 + 2]; cur.w += Sf[dd*64 + v*4 + 3];
    *(float4*)(&out[p]) = cur;
  }
}

extern "C" void kernel_launch(void* const* d_in, const int* in_sizes, int n_in,
                              void* d_out, int out_size, void* d_ws, size_t ws_size,
                              hipStream_t stream) {
  const float* x  = (const float*)d_in[0];
  const float* Wq = (const float*)d_in[1];
  const float* EF = (const float*)d_in[2];
  const float* t1 = (const float*)d_in[3];
  const float* t2 = (const float*)d_in[4];
  float* out = (float*)d_out;

  u16* Xb  = (u16*)d_ws;                 // 16384*512 (dead after k_gemm)
  u16* Wb  = Xb + 8388608;               // 2048*512
  u16* EFt = Wb + 1048576;               // 64*4096
  u16* QK  = EFt + 262144;               // 2048*16384
  float* rq  = (float*)(QK + 33554432);  // 4*512
  float* rk  = rq + 2048;                // 4*512
  u16* kpb = (u16*)(rk + 2048);          // 32*64*64 bf16 [bh][kk][dd], pre-scaled rq*t2, pre-swizzled
  u16* vpb = kpb + 131072;               // 32*64*64 bf16 [bh][dd][kk], pre-swizzled
  u16* Pca = vpb + 131072;               // 32*64*64 bf16, pre-swizzled
  float* Pp = (float*)d_ws;              // partials [bh][3][8][4096] f32, aliases Xb

  k_convert<<<10240, 256, 0, stream>>>((const float4*)x, (const float4*)Wq, EF, Xb, Wb, EFt);
  k_gemm   <<<512,  512, 0, stream>>>(Wb, Xb, QK);
  k_rnorm  <<<1024, 256, 0, stream>>>(QK, rq, rk);
  k_acc1   <<<768,  256, 0, stream>>>(QK, EFt, Pp);
  k_fin    <<<128,  256, 0, stream>>>(Pp, rq, rk, t1, t2, Pca, kpb, vpb);
  k_ca_pv  <<<2048, 256, 0, stream>>>(QK, Pca, out);
  k_sa     <<<2048, 256, 0, stream>>>(QK, kpb, vpb, out);
}